// Round 4
// baseline (81692.804 us; speedup 1.0000x reference)
//
#include <hip/hip_runtime.h>
#include <hip/hip_bf16.h>

// LSTM (2-layer, T=1024) + STE binarize + FC, MI355X.
// Round 4: per-XCD leader-staged h distribution. Leaders pull h slices from
// the coherent point once per XCD (16 MB/phase fabric vs 196 MB in R3) into
// L2-resident scratch; all blocks read from local L2 (sc0 = L1-bypass).
// kq-split waves (8 K-slices x all 4 gates): A dup 1x, B dup 1x.
// Dynamic XCD placement via HW_REG_XCC_ID + atomic slot claim; LDS 147 KB
// forces 1 block/CU => exactly 32 blocks/XCD.

typedef _Float16 f16;
typedef __attribute__((ext_vector_type(8))) _Float16 f16x8;
typedef __attribute__((ext_vector_type(4))) float f32x4;

#define MFMA(a, b, c) __builtin_amdgcn_mfma_f32_16x16x32_f16((a), (b), (c), 0, 0, 0)
#define H8(v) __builtin_bit_cast(f16x8, v)

// coherent-point (MALL) read: bypass L1+L2
#define GLB(dst, ptr) asm volatile("global_load_dwordx4 %0, %1, off sc0 sc1" : "=v"(dst) : "v"(ptr) : "memory")
// L2-served read, L1 bypass (fresh within XCD)
#define GLS(dst, ptr) asm volatile("global_load_dwordx4 %0, %1, off sc0" : "=v"(dst) : "v"(ptr) : "memory")
// plain cached read (immutable weights)
#define GLC(dst, ptr) asm volatile("global_load_dwordx4 %0, %1, off" : "=v"(dst) : "v"(ptr) : "memory")
// store that stays resident+dirty in local L2 (scratch)
#define GSS(ptr, val) asm volatile("global_store_dwordx4 %0, %1, off sc0" :: "v"(ptr), "v"(val) : "memory")
#define VMWAIT(n) do { asm volatile("s_waitcnt vmcnt(" #n ")" ::: "memory"); __builtin_amdgcn_sched_barrier(0); } while (0)
#define DRAIN() do { asm volatile("s_waitcnt vmcnt(0)" ::: "memory"); __builtin_amdgcn_sched_barrier(0); } while (0)

#define NB 512
#define NT 1024
#define NF 128
#define NH 512
#define NGC 2048
#define K0 640      // NH + NF   (L0: [h0_prev | x_t])
#define K1 1024     // 2*NH      (L1: [h0_t | h1_prev])
#define HBUF 262144 // NB*NH elements
#define NBLK 256
#define NTHR 512
#define GS0 655360   // gate stride bytes in W0 (NH*K0*2)
#define GS1 1048576  // gate stride bytes in W1 (NH*K1*2)
#define GETREG_XCC 63508  // hwreg(HW_REG_XCC_ID=20, 0, 32)

__device__ __forceinline__ float sigf(float v) { return 1.0f / (1.0f + expf(-v)); }

// coherent 4B (f16x2) write-through store (h state -> MALL)
__device__ __forceinline__ void cstore2(f16* p, f16 a, f16 b) {
    union { f16 h[2]; unsigned u; } x;
    x.h[0] = a; x.h[1] = b;
    __hip_atomic_store((unsigned*)p, x.u, __ATOMIC_RELAXED, __HIP_MEMORY_SCOPE_AGENT);
}

// fragment-native element index: [rowblk r>>4][kblk c>>5][lane=((c>>3)&3)*16+(r&15)][c&7]
__device__ __forceinline__ size_t hidx(int r, int c) {
    return ((size_t)(((r >> 4) * 16 + (c >> 5)) * 64 + ((c >> 3) & 3) * 16 + (r & 15))) * 8 + (c & 7);
}

__device__ __forceinline__ void splitr(f32x4 u0, f32x4 u1, f16x8& hi, f16x8& lo) {
#pragma unroll
    for (int e = 0; e < 4; ++e) {
        float v = u0[e];
        f16 h = (f16)v;
        hi[e] = h;
        lo[e] = (f16)(v - (float)h);
    }
#pragma unroll
    for (int e = 0; e < 4; ++e) {
        float v = u1[e];
        f16 h = (f16)v;
        hi[4 + e] = h;
        lo[4 + e] = (f16)(v - (float)h);
    }
}

// ---------------- prep: split weights into packed hi/lo f16, sum biases ----------------
__global__ __launch_bounds__(256) void prep_kernel(
    const float* __restrict__ Wih0, const float* __restrict__ Whh0,
    const float* __restrict__ bih0, const float* __restrict__ bhh0,
    const float* __restrict__ Wih1, const float* __restrict__ Whh1,
    const float* __restrict__ bih1, const float* __restrict__ bhh1,
    f16* __restrict__ W0h, f16* __restrict__ W0l,
    f16* __restrict__ W1h, f16* __restrict__ W1l,
    float* __restrict__ bias0, float* __restrict__ bias1)
{
    const int stride = gridDim.x * blockDim.x;
    const int idx = blockIdx.x * blockDim.x + threadIdx.x;
    const int total0 = NGC * K0;
    for (int i = idx; i < total0; i += stride) {
        int gc = i / K0, k = i - gc * K0;
        float w = (k < NH) ? Whh0[gc * NH + k] : Wih0[gc * NF + (k - NH)];
        f16 h = (f16)w;
        W0h[i] = h;
        W0l[i] = (f16)(w - (float)h);
    }
    const int total1 = NGC * K1;
    for (int i = idx; i < total1; i += stride) {
        int gc = i / K1, k = i - gc * K1;
        float w = (k < NH) ? Wih1[gc * NH + k] : Whh1[gc * NH + (k - NH)];
        f16 h = (f16)w;
        W1h[i] = h;
        W1l[i] = (f16)(w - (float)h);
    }
    for (int i = idx; i < NGC; i += stride) {
        bias0[i] = bih0[i] + bhh0[i];
        bias1[i] = bih1[i] + bhh1[i];
    }
}

struct Stg { f32x4 A[8]; f32x4 B[8]; }; // A: 4 rowblocks x hi/lo; B: 4 gates x hi/lo

// one K-step (32 k) from scratch h0 + W0; _o/_b byte offsets
#define ISSUE0(S, s_) do { \
    const int _o = kq * 2048 + (s_) * 1024; \
    GLS(S.A[0], a0h + _o);          GLS(S.A[1], a0l + _o); \
    GLS(S.A[2], a0h + _o + 16384);  GLS(S.A[3], a0l + _o + 16384); \
    GLS(S.A[4], a0h + _o + 32768);  GLS(S.A[5], a0l + _o + 32768); \
    GLS(S.A[6], a0h + _o + 49152);  GLS(S.A[7], a0l + _o + 49152); \
    const int _b = kq * 128 + (s_) * 64; \
    GLC(S.B[0], w0hB + _b);             GLC(S.B[1], w0lB + _b); \
    GLC(S.B[2], w0hB + _b + GS0);       GLC(S.B[3], w0lB + _b + GS0); \
    GLC(S.B[4], w0hB + _b + 2 * GS0);   GLC(S.B[5], w0lB + _b + 2 * GS0); \
    GLC(S.B[6], w0hB + _b + 3 * GS0);   GLC(S.B[7], w0lB + _b + 3 * GS0); \
} while (0)

// one K-step from scratch (h0 for kq<4, h1 for kq>=4) + W1
#define ISSUE1(S, s_) do { \
    const int _o = (kq & 3) * 4096 + (s_) * 1024; \
    GLS(S.A[0], a1h + _o);          GLS(S.A[1], a1l + _o); \
    GLS(S.A[2], a1h + _o + 16384);  GLS(S.A[3], a1l + _o + 16384); \
    GLS(S.A[4], a1h + _o + 32768);  GLS(S.A[5], a1l + _o + 32768); \
    GLS(S.A[6], a1h + _o + 49152);  GLS(S.A[7], a1l + _o + 49152); \
    const int _b = kq * 256 + (s_) * 64; \
    GLC(S.B[0], w1hB + _b);             GLC(S.B[1], w1lB + _b); \
    GLC(S.B[2], w1hB + _b + GS1);       GLC(S.B[3], w1lB + _b + GS1); \
    GLC(S.B[4], w1hB + _b + 2 * GS1);   GLC(S.B[5], w1lB + _b + 2 * GS1); \
    GLC(S.B[6], w1hB + _b + 3 * GS1);   GLC(S.B[7], w1lB + _b + 3 * GS1); \
} while (0)

// 48 MFMAs: 4 gates x 4 rowblock-frags x 3 split-products
#define STEPALL(S) do { \
    _Pragma("unroll") for (int g = 0; g < 4; ++g) \
    _Pragma("unroll") for (int f = 0; f < 4; ++f) { \
        acc[g][f] = MFMA(H8(S.A[f * 2]),     H8(S.B[g * 2]),     acc[g][f]); \
        acc[g][f] = MFMA(H8(S.A[f * 2]),     H8(S.B[g * 2 + 1]), acc[g][f]); \
        acc[g][f] = MFMA(H8(S.A[f * 2 + 1]), H8(S.B[g * 2]),     acc[g][f]); \
    } } while (0)

#define ZACC() do { f32x4 _z = {0.f, 0.f, 0.f, 0.f}; \
    _Pragma("unroll") for (int g = 0; g < 4; ++g) \
    _Pragma("unroll") for (int f = 0; f < 4; ++f) acc[g][f] = _z; } while (0)

#define DUMPG() do { \
    _Pragma("unroll") for (int g = 0; g < 4; ++g) \
    _Pragma("unroll") for (int f = 0; f < 4; ++f) \
    _Pragma("unroll") for (int rg = 0; rg < 4; ++rg) \
        ldsG[kq][g][f * 16 + kg * 4 + rg][lm] = acc[g][f][rg]; } while (0)

// ---------------- main persistent LSTM kernel ----------------
__global__ __launch_bounds__(NTHR, 2) void lstm_kernel(
    const float* __restrict__ x,
    const f16* __restrict__ W0h, const f16* __restrict__ W0l,
    const f16* __restrict__ W1h, const f16* __restrict__ W1l,
    const float* __restrict__ bias0, const float* __restrict__ bias1,
    f16* hb, f16* scratch, unsigned* sync,
    float* __restrict__ h1f)
{
    const int tid = threadIdx.x;
    const int lane = tid & 63;
    const int kq = tid >> 6;     // wave = K-slice 0..7
    const int kg = lane >> 4;    // k-subgroup within 32
    const int lm = lane & 15;

    __shared__ float ldsG[8][4][64][18]; // [kq][gate][row][col] partials (147456 B -> 1 block/CU)
    __shared__ int sSlot;

    // ---- dynamic placement: real XCD + slot claim ----
    const unsigned xcd = (unsigned)__builtin_amdgcn_s_getreg(GETREG_XCC) & 7u;
    unsigned* gbar    = sync;                 // global barrier counter
    unsigned* slotCtr = sync + 128 + xcd * 64; // 256B-spaced per-XCD claim counters
    unsigned* xbarCtr = sync + 1024 + xcd * 64; // per-XCD barrier counters
    if (tid == 0) sSlot = (int)__hip_atomic_fetch_add(slotCtr, 1u, __ATOMIC_RELAXED, __HIP_MEMORY_SCOPE_AGENT);
    __syncthreads();
    const int slot = sSlot;          // 0..31 within this XCD
    const int rowTile = slot >> 2;   // 0..7
    const int colW = slot & 3;       // 0..3
    const int colTile = (int)xcd * 4 + colW; // 0..31
    const int row0 = rowTile * 64;
    const bool leader = (colW == 0);

    // per-XCD scratch arrays (frag-native full-matrix layout)
    char* scrBase = (char*)(scratch + (size_t)xcd * 4 * HBUF);
    char* scr0h = scrBase;
    char* scr0l = scrBase + (size_t)HBUF * 2;
    char* scr1h = scrBase + (size_t)HBUF * 4;
    char* scr1l = scrBase + (size_t)HBUF * 6;

    // A-fragment base pointers (scratch, this block's rowTile, this lane)
    const size_t aOff = (size_t)rowTile * 65536 + (size_t)lane * 16;
    const char* a0h = scr0h + aOff;
    const char* a0l = scr0l + aOff;
    const char* a1h = (kq < 4 ? scr0h : scr1h) + aOff;
    const char* a1l = (kq < 4 ? scr0l : scr1l) + aOff;

    // B weight base pointers (gate 0 column for this lane)
    const char* w0hB = (const char*)W0h + ((size_t)(colTile * 16 + lm) * K0 + kg * 8) * 2;
    const char* w0lB = (const char*)W0l + ((size_t)(colTile * 16 + lm) * K0 + kg * 8) * 2;
    const char* w1hB = (const char*)W1h + ((size_t)(colTile * 16 + lm) * K1 + kg * 8) * 2;
    const char* w1lB = (const char*)W1l + ((size_t)(colTile * 16 + lm) * K1 + kg * 8) * 2;

    // epilogue mapping (each thread: 1 row x 2 cols)
    const int er = tid >> 3;
    const int ej = (tid & 7) * 2;
    const int ecol = colTile * 16 + ej;
    const size_t eoff = hidx(row0 + er, ecol);
    float bL0[4][2], bL1[4][2];
#pragma unroll
    for (int g = 0; g < 4; ++g)
#pragma unroll
        for (int e = 0; e < 2; ++e) {
            bL0[g][e] = bias0[g * NH + ecol + e];
            bL1[g][e] = bias1[g * NH + ecol + e];
        }

    float c0[2] = {0.f, 0.f}, c1[2] = {0.f, 0.f};
    f32x4 acc[4][4];
    Stg sA, sB;

    for (int p = 0; p <= NT; ++p) {
        const int pb_ = (p - 1) & 1;
        const int cb_ = p & 1;
        const char* h0hG = (const char*)(hb + (size_t)(0 + pb_) * HBUF);
        const char* h0lG = (const char*)(hb + (size_t)(2 + pb_) * HBUF);
        const char* h1hG = (const char*)(hb + (size_t)(4 + cb_) * HBUF);
        const char* h1lG = (const char*)(hb + (size_t)(6 + cb_) * HBUF);

        // ---- leader: pull this rowTile's h slices from MALL into local-L2 scratch ----
        if (leader) {
            const size_t co = (size_t)rowTile * 65536 + (size_t)tid * 16;
            f32x4 tA0, tA1, tA2, tA3, tA4, tA5, tA6, tA7;
            f32x4 tB0, tB1, tB2, tB3, tB4, tB5, tB6, tB7;
            f32x4 tC0, tC1, tC2, tC3, tC4, tC5, tC6, tC7;
            f32x4 tD0, tD1, tD2, tD3, tD4, tD5, tD6, tD7;
#define LD8(T, src) do { const char* _s = (src) + co; \
    GLB(T##0, _s); GLB(T##1, _s + 8192); GLB(T##2, _s + 16384); GLB(T##3, _s + 24576); \
    GLB(T##4, _s + 32768); GLB(T##5, _s + 40960); GLB(T##6, _s + 49152); GLB(T##7, _s + 57344); } while (0)
#define ST8(T, dst) do { char* _d = (dst) + co; \
    GSS(_d, T##0); GSS(_d + 8192, T##1); GSS(_d + 16384, T##2); GSS(_d + 24576, T##3); \
    GSS(_d + 32768, T##4); GSS(_d + 40960, T##5); GSS(_d + 49152, T##6); GSS(_d + 57344, T##7); } while (0)
            LD8(tA, h0hG); LD8(tB, h0lG);
            VMWAIT(8);  ST8(tA, scr0h); LD8(tC, h1hG);
            VMWAIT(16); ST8(tB, scr0l); LD8(tD, h1lG);
            VMWAIT(16); ST8(tC, scr1h);
            VMWAIT(8);  ST8(tD, scr1l);
#undef LD8
#undef ST8
        }

        // ---- x-part of L0 (waves 4..7), overlapped with leader copy ----
        ZACC();
        if (p < NT && kq >= 4) {
            const int xb = (kq - 4) * 32; // feature base
            f16x8 Bh[4], Bl[4];
#pragma unroll
            for (int g = 0; g < 4; ++g) {
                Bh[g] = *(const f16x8*)(W0h + (size_t)(g * NH + colTile * 16 + lm) * K0 + NH + xb + kg * 8);
                Bl[g] = *(const f16x8*)(W0l + (size_t)(g * NH + colTile * 16 + lm) * K0 + NH + xb + kg * 8);
            }
#pragma unroll
            for (int f = 0; f < 4; ++f) {
                const float* px = x + ((size_t)(row0 + f * 16 + lm) * NT + p) * NF + xb + kg * 8;
                f32x4 u0 = *(const f32x4*)px;
                f32x4 u1 = *(const f32x4*)(px + 4);
                f16x8 Ah, Al;
                splitr(u0, u1, Ah, Al);
#pragma unroll
                for (int g = 0; g < 4; ++g) {
                    acc[g][f] = MFMA(Ah, Bh[g], acc[g][f]);
                    acc[g][f] = MFMA(Ah, Bl[g], acc[g][f]);
                    acc[g][f] = MFMA(Al, Bh[g], acc[g][f]);
                }
            }
        }
        DRAIN();

        // ---- XCD barrier: scratch ready for all 32 blocks on this XCD ----
        __syncthreads();
        if (tid == 0) {
            __hip_atomic_fetch_add(xbarCtr, 1u, __ATOMIC_RELAXED, __HIP_MEMORY_SCOPE_AGENT);
            const unsigned tgt = (unsigned)(p + 1) * 32u;
            while (__hip_atomic_load(xbarCtr, __ATOMIC_RELAXED, __HIP_MEMORY_SCOPE_AGENT) < tgt) {
                __builtin_amdgcn_s_sleep(1);
            }
        }
        __syncthreads();
        asm volatile("" ::: "memory");

        // ================= L0 h-GEMM (2 K-steps per wave, counted pipeline) =================
        if (p < NT) {
            ISSUE0(sA, 0);
            ISSUE0(sB, 1);
            VMWAIT(16); STEPALL(sA);
            DRAIN();    STEPALL(sB);
            DUMPG();
        }
        __syncthreads();
        // ---- cell L0 ----
        if (p < NT) {
            float gs[4][2];
#pragma unroll
            for (int g = 0; g < 4; ++g) { gs[g][0] = bL0[g][0]; gs[g][1] = bL0[g][1]; }
#pragma unroll
            for (int q = 0; q < 8; ++q)
#pragma unroll
                for (int g = 0; g < 4; ++g) {
                    float2 v = *(const float2*)&ldsG[q][g][er][ej];
                    gs[g][0] += v.x; gs[g][1] += v.y;
                }
            f16 hh[2], hl[2];
#pragma unroll
            for (int e = 0; e < 2; ++e) {
                const float cn = sigf(gs[1][e]) * c0[e] + sigf(gs[0][e]) * tanhf(gs[2][e]);
                c0[e] = cn;
                const float h = sigf(gs[3][e]) * tanhf(cn);
                hh[e] = (f16)h;
                hl[e] = (f16)(h - (float)hh[e]);
            }
            cstore2(hb + (size_t)(0 + cb_) * HBUF + eoff, hh[0], hh[1]);
            cstore2(hb + (size_t)(2 + cb_) * HBUF + eoff, hl[0], hl[1]);
        }
        __syncthreads();
        // ================= L1 GEMM (4 K-steps per wave) =================
        if (p >= 1) {
            ZACC();
            ISSUE1(sA, 0);
            ISSUE1(sB, 1);
            VMWAIT(16); STEPALL(sA);
            ISSUE1(sA, 2);
            VMWAIT(16); STEPALL(sB);
            ISSUE1(sB, 3);
            VMWAIT(16); STEPALL(sA);
            DRAIN();    STEPALL(sB);
            DUMPG();
        }
        __syncthreads();
        // ---- cell L1 ----
        if (p >= 1) {
            float gs[4][2];
#pragma unroll
            for (int g = 0; g < 4; ++g) { gs[g][0] = bL1[g][0]; gs[g][1] = bL1[g][1]; }
#pragma unroll
            for (int q = 0; q < 8; ++q)
#pragma unroll
                for (int g = 0; g < 4; ++g) {
                    float2 v = *(const float2*)&ldsG[q][g][er][ej];
                    gs[g][0] += v.x; gs[g][1] += v.y;
                }
            f16 hh[2], hl[2];
            float hv[2];
#pragma unroll
            for (int e = 0; e < 2; ++e) {
                const float cn = sigf(gs[1][e]) * c1[e] + sigf(gs[0][e]) * tanhf(gs[2][e]);
                c1[e] = cn;
                const float h = sigf(gs[3][e]) * tanhf(cn);
                hv[e] = h;
                hh[e] = (f16)h;
                hl[e] = (f16)(h - (float)hh[e]);
            }
            cstore2(hb + (size_t)(4 + pb_) * HBUF + eoff, hh[0], hh[1]);
            cstore2(hb + (size_t)(6 + pb_) * HBUF + eoff, hl[0], hl[1]);
            if (p == NT) {
                const size_t off = (size_t)(row0 + er) * NH + ecol;
                h1f[off] = hv[0];
                h1f[off + 1] = hv[1];
            }
        }
        // ================= global barrier =================
        if (p < NT) {
            __syncthreads(); // drains vmcnt: h writes visible at coherent point
            if (tid == 0) {
                __hip_atomic_fetch_add(gbar, 1u, __ATOMIC_RELAXED, __HIP_MEMORY_SCOPE_AGENT);
                const unsigned tgt = (unsigned)(p + 1) * NBLK;
                while (__hip_atomic_load(gbar, __ATOMIC_RELAXED, __HIP_MEMORY_SCOPE_AGENT) < tgt) {
                    __builtin_amdgcn_s_sleep(1);
                }
            }
            __syncthreads();
            asm volatile("" ::: "memory");
        }
    }
}

// ---------------- binarize + FC ----------------
__global__ __launch_bounds__(256) void fc_kernel(
    const float* __restrict__ h1f, const float* __restrict__ Wfc,
    const float* __restrict__ bfc, float* __restrict__ out)
{
    const int t = blockIdx.x * blockDim.x + threadIdx.x; // 0..16383
    const int b = t >> 5;
    const int o = t & 31;
    const float4* hr = (const float4*)(h1f + (size_t)b * NH);
    const float4* wr = (const float4*)(Wfc + (size_t)o * NH);
    float s = 0.f;
#pragma unroll 4
    for (int j = 0; j < NH / 4; ++j) {
        float4 h4 = hr[j];
        float4 w4 = wr[j];
        s += (h4.x > 0.f ? w4.x : 0.f) + (h4.y > 0.f ? w4.y : 0.f)
           + (h4.z > 0.f ? w4.z : 0.f) + (h4.w > 0.f ? w4.w : 0.f);
    }
    out[t] = s + bfc[o];
}

extern "C" void kernel_launch(void* const* d_in, const int* in_sizes, int n_in,
                              void* d_out, int out_size, void* d_ws, size_t ws_size,
                              hipStream_t stream) {
    const float* x    = (const float*)d_in[0];
    const float* Wih0 = (const float*)d_in[1];
    const float* Whh0 = (const float*)d_in[2];
    const float* bih0 = (const float*)d_in[3];
    const float* bhh0 = (const float*)d_in[4];
    const float* Wih1 = (const float*)d_in[5];
    const float* Whh1 = (const float*)d_in[6];
    const float* bih1 = (const float*)d_in[7];
    const float* bhh1 = (const float*)d_in[8];
    const float* Wfc  = (const float*)d_in[9];
    const float* bfc  = (const float*)d_in[10];
    float* out = (float*)d_out;
    (void)in_sizes; (void)n_in; (void)out_size; (void)ws_size;

    // workspace layout (~35 MB)
    char* w = (char*)d_ws;
    unsigned* sync = (unsigned*)w;                                   // 8 KB sync region
    f16* hb = (f16*)(w + 8192);                                      // 4 MB h ping-pong (hi/lo)
    f16* scratch = (f16*)(w + 8192 + (size_t)8 * HBUF * 2);          // 16 MB per-XCD L2 scratch
    char* after = w + 8192 + (size_t)8 * HBUF * 2 + (size_t)32 * HBUF * 2;
    float* h1f = (float*)after;                                      // 1 MB
    float* bias0 = (float*)(after + (size_t)NB * NH * 4);
    float* bias1 = bias0 + NGC;
    f16* W0h = (f16*)(bias1 + NGC);
    f16* W0l = W0h + (size_t)NGC * K0;
    f16* W1h = W0l + (size_t)NGC * K0;
    f16* W1l = W1h + (size_t)NGC * K1;

    // zero: sync counters + h state (h(-1)=0); replayed each graph launch
    hipMemsetAsync(d_ws, 0, 8192 + (size_t)8 * HBUF * 2, stream);

    prep_kernel<<<2048, 256, 0, stream>>>(Wih0, Whh0, bih0, bhh0, Wih1, Whh1, bih1, bhh1,
                                          W0h, W0l, W1h, W1l, bias0, bias1);

    lstm_kernel<<<NBLK, NTHR, 0, stream>>>(x, W0h, W0l, W1h, W1l, bias0, bias1,
                                           hb, scratch, sync, h1f);

    fc_kernel<<<64, 256, 0, stream>>>(h1f, Wfc, bfc, out);
}

// Round 5
// 53066.602 us; speedup vs baseline: 1.5394x; 1.5394x over previous
//
#include <hip/hip_runtime.h>
#include <hip/hip_bf16.h>

// LSTM (2-layer, T=1024) + STE binarize + FC, MI355X.
// Round 5: direct MALL-bypass h reads (R3 path), restructured to cut fabric
// traffic 4x: 32x32 tiles (16 rowTiles x 16 colTiles) + per-layer kq-split
// waves (A dup 1x). Both layers' GEMMs in one section per phase (L1 needs
// only h0(p-1), h1(p-2)). Counted vmcnt pipeline, lookahead-2 on fabric A.
// Two-level tree grid barrier.

typedef _Float16 f16;
typedef __attribute__((ext_vector_type(8))) _Float16 f16x8;
typedef __attribute__((ext_vector_type(4))) float f32x4;

#define MFMA(a, b, c) __builtin_amdgcn_mfma_f32_16x16x32_f16((a), (b), (c), 0, 0, 0)
#define H8(v) __builtin_bit_cast(f16x8, v)

// MALL-coherent bypass load (no L1/L2 allocation)
#define GLB(dst, ptr) asm volatile("global_load_dwordx4 %0, %1, off sc0 sc1" : "=v"(dst) : "v"(ptr) : "memory")
// cached load (weights / x)
#define GLC(dst, ptr) asm volatile("global_load_dwordx4 %0, %1, off" : "=v"(dst) : "v"(ptr) : "memory")
#define VMW(n) do { asm volatile("s_waitcnt vmcnt(" #n ")" ::: "memory"); __builtin_amdgcn_sched_barrier(0); } while (0)

#define NB 512
#define NT 1024
#define NF 128
#define NH 512
#define NGC 2048
#define K0 640      // NH + NF   (L0: [h0_prev | x_t])
#define K1 1024     // 2*NH      (L1: [h0_t | h1_prev])
#define HBUF 262144 // NB*NH elements per h half-buffer
#define HB2 524288  // HBUF bytes (f16)
#define NBLK 256
#define NTHR 512
// byte strides in packed weights
#define GS0 655360   // gate stride W0: NH*K0*2
#define CS0 20480    // 16-col stride W0: 16*K0*2
#define GS1 1048576  // gate stride W1: NH*K1*2
#define CS1 32768    // 16-col stride W1: 16*K1*2

__device__ __forceinline__ float sigf(float v) { return 1.0f / (1.0f + expf(-v)); }

// coherent 4B (f16x2) write-through store (h state -> MALL)
__device__ __forceinline__ void cstore2(f16* p, f16 a, f16 b) {
    union { f16 h[2]; unsigned u; } x;
    x.h[0] = a; x.h[1] = b;
    __hip_atomic_store((unsigned*)p, x.u, __ATOMIC_RELAXED, __HIP_MEMORY_SCOPE_AGENT);
}

// fragment-native element index: [rowblk r>>4][kblk c>>5][lane=((c>>3)&3)*16+(r&15)][c&7]
__device__ __forceinline__ size_t hidx(int r, int c) {
    return ((size_t)(((r >> 4) * 16 + (c >> 5)) * 64 + ((c >> 3) & 3) * 16 + (r & 15))) * 8 + (c & 7);
}

__device__ __forceinline__ void splitr(f32x4 u0, f32x4 u1, f16x8& hi, f16x8& lo) {
#pragma unroll
    for (int e = 0; e < 4; ++e) {
        float v = u0[e];
        f16 h = (f16)v;
        hi[e] = h;
        lo[e] = (f16)(v - (float)h);
    }
#pragma unroll
    for (int e = 0; e < 4; ++e) {
        float v = u1[e];
        f16 h = (f16)v;
        hi[4 + e] = h;
        lo[4 + e] = (f16)(v - (float)h);
    }
}

// ---------------- prep: split weights into packed hi/lo f16, sum biases ----------------
__global__ __launch_bounds__(256) void prep_kernel(
    const float* __restrict__ Wih0, const float* __restrict__ Whh0,
    const float* __restrict__ bih0, const float* __restrict__ bhh0,
    const float* __restrict__ Wih1, const float* __restrict__ Whh1,
    const float* __restrict__ bih1, const float* __restrict__ bhh1,
    f16* __restrict__ W0h, f16* __restrict__ W0l,
    f16* __restrict__ W1h, f16* __restrict__ W1l,
    float* __restrict__ bias0, float* __restrict__ bias1)
{
    const int stride = gridDim.x * blockDim.x;
    const int idx = blockIdx.x * blockDim.x + threadIdx.x;
    const int total0 = NGC * K0;
    for (int i = idx; i < total0; i += stride) {
        int gc = i / K0, k = i - gc * K0;
        float w = (k < NH) ? Whh0[gc * NH + k] : Wih0[gc * NF + (k - NH)];
        f16 h = (f16)w;
        W0h[i] = h;
        W0l[i] = (f16)(w - (float)h);
    }
    const int total1 = NGC * K1;
    for (int i = idx; i < total1; i += stride) {
        int gc = i / K1, k = i - gc * K1;
        float w = (k < NH) ? Wih1[gc * NH + k] : Whh1[gc * NH + (k - NH)];
        f16 h = (f16)w;
        W1h[i] = h;
        W1l[i] = (f16)(w - (float)h);
    }
    for (int i = idx; i < NGC; i += stride) {
        bias0[i] = bih0[i] + bhh0[i];
        bias1[i] = bih1[i] + bhh1[i];
    }
}

// issue one A k-step (4 bypass loads: 2 rowfrags x hi/lo) into Ast[buf]
#define ISSA(buf, ko) do { \
    GLB(Ast[buf][0], aH + (ko));         GLB(Ast[buf][1], aL + (ko)); \
    GLB(Ast[buf][2], aH + (ko) + 16384); GLB(Ast[buf][3], aL + (ko) + 16384); \
} while (0)

// issue one B half-step (8 cached loads: 2 gates x 2 col-halves x hi/lo)
#define ISSB(c, ph, pl, GS, CS, hf, ko) do { \
    _Pragma("unroll") for (int gi = 0; gi < 2; ++gi) \
    _Pragma("unroll") for (int ch = 0; ch < 2; ++ch) { \
        GLC(Bst[c][(gi * 2 + ch) * 2],     (ph) + (size_t)((hf) * 2 + gi) * (GS) + (size_t)ch * (CS) + (ko)); \
        GLC(Bst[c][(gi * 2 + ch) * 2 + 1], (pl) + (size_t)((hf) * 2 + gi) * (GS) + (size_t)ch * (CS) + (ko)); \
    } } while (0)

// 24 MFMAs: 2 gates x 2 col-halves x 2 rowfrags x 3 split-products
#define MFS(c, ab, hf) do { \
    _Pragma("unroll") for (int gi = 0; gi < 2; ++gi) \
    _Pragma("unroll") for (int ch = 0; ch < 2; ++ch) \
    _Pragma("unroll") for (int rf = 0; rf < 2; ++rf) { \
        const int cf = ((hf) * 2 + gi) * 2 + ch; \
        acc[cf][rf] = MFMA(H8(Ast[ab][rf * 2]),     H8(Bst[c][(gi * 2 + ch) * 2]),     acc[cf][rf]); \
        acc[cf][rf] = MFMA(H8(Ast[ab][rf * 2]),     H8(Bst[c][(gi * 2 + ch) * 2 + 1]), acc[cf][rf]); \
        acc[cf][rf] = MFMA(H8(Ast[ab][rf * 2 + 1]), H8(Bst[c][(gi * 2 + ch) * 2]),     acc[cf][rf]); \
    } } while (0)

// x variant (A from split registers)
#define MFX(c, hf) do { \
    _Pragma("unroll") for (int gi = 0; gi < 2; ++gi) \
    _Pragma("unroll") for (int ch = 0; ch < 2; ++ch) \
    _Pragma("unroll") for (int rf = 0; rf < 2; ++rf) { \
        const int cf = ((hf) * 2 + gi) * 2 + ch; \
        acc[cf][rf] = MFMA(XAh[rf], H8(Bst[c][(gi * 2 + ch) * 2]),     acc[cf][rf]); \
        acc[cf][rf] = MFMA(XAh[rf], H8(Bst[c][(gi * 2 + ch) * 2 + 1]), acc[cf][rf]); \
        acc[cf][rf] = MFMA(XAl[rf], H8(Bst[c][(gi * 2 + ch) * 2]),     acc[cf][rf]); \
    } } while (0)

#define ZACC() do { f32x4 _z = {0.f, 0.f, 0.f, 0.f}; \
    _Pragma("unroll") for (int cf = 0; cf < 8; ++cf) { acc[cf][0] = _z; acc[cf][1] = _z; } } while (0)

#define DUMP() do { \
    _Pragma("unroll") for (int cf = 0; cf < 8; ++cf) \
    _Pragma("unroll") for (int rf = 0; rf < 2; ++rf) \
    _Pragma("unroll") for (int rg = 0; rg < 4; ++rg) \
        ldsP[w][rf * 16 + kg * 4 + rg][cf * 16 + lm] = acc[cf][rf][rg]; } while (0)

// ---------------- main persistent LSTM kernel ----------------
__global__ __launch_bounds__(NTHR, 2) void lstm_kernel(
    const float* __restrict__ x,
    const f16* __restrict__ W0h, const f16* __restrict__ W0l,
    const f16* __restrict__ W1h, const f16* __restrict__ W1l,
    const float* __restrict__ bias0, const float* __restrict__ bias1,
    f16* hb, unsigned* sync,
    float* __restrict__ h1f)
{
    const int tid = threadIdx.x;
    const int bid = blockIdx.x;
    const int lane = tid & 63;
    const int w = tid >> 6;      // wave 0..7
    const int Lg = w >> 2;       // 0: layer0 waves, 1: layer1 waves
    const int kq = w & 3;        // K-quarter within layer
    const int kg = lane >> 4;    // k-subgroup within 32
    const int lm = lane & 15;

    // XCD-aware tile map: 2 colTiles per XCD (weights ~1.7MB L2-resident)
    const int xcd = bid & 7;
    const int s = bid >> 3;                  // 0..31
    const int colTile = xcd * 2 + (s & 1);   // 0..15 (32 h-cols each)
    const int rowTile = s >> 1;              // 0..15 (32 rows each)
    const int row0 = rowTile * 32;
    const int rb0 = rowTile * 2;
    const int grp = bid >> 5;                // barrier group 0..7

    __shared__ float ldsP[8][32][132]; // [wave][row][gc 0..127 +pad] partials

    // B standing pointers: gate-0, col-half-0 column for this lane, at wave's k-base
    const int gcb = colTile * 32 + lm;
    const char *bh, *bl;
    if (Lg == 0) {
        const size_t o = ((size_t)gcb * K0 + kq * 128 + kg * 8) * 2;
        bh = (const char*)W0h + o; bl = (const char*)W0l + o;
    } else {
        const size_t o = ((size_t)gcb * K1 + kq * 256 + kg * 8) * 2;
        bh = (const char*)W1h + o; bl = (const char*)W1l + o;
    }
    // x-part B pointers (L0 waves)
    const size_t xko = ((size_t)gcb * K0 + NH + kq * 32 + kg * 8) * 2;
    const char* xbh = (const char*)W0h + xko;
    const char* xbl = (const char*)W0l + xko;

    // x A pointers (advance 512 B per phase)
    const char* pxa0 = (const char*)x + ((size_t)(row0 + lm) * NT) * NF * 4 + (size_t)(kq * 32 + kg * 8) * 4;
    const char* pxa1 = pxa0 + (size_t)16 * NT * NF * 4;

    // A byte offset within an h buffer (rowblk/kblk frag layout)
    const size_t aoff = (Lg == 0)
        ? ((size_t)(rb0 * 16 + kq * 4) * 1024 + (size_t)lane * 16)
        : ((size_t)(rb0 * 16 + (kq & 1) * 8) * 1024 + (size_t)lane * 16);

    char* hbB = (char*)hb;

    // epilogue mapping: thread -> (row er, col pair ec2) for both layers
    const int er = tid >> 4;          // 0..31
    const int ec2 = (tid & 15) * 2;   // 0..30
    const int ecol = colTile * 32 + ec2;
    const size_t eoff = hidx(row0 + er, ecol);
    float bE[2][4][2];
#pragma unroll
    for (int g = 0; g < 4; ++g)
#pragma unroll
        for (int e = 0; e < 2; ++e) {
            bE[0][g][e] = bias0[g * NH + ecol + e];
            bE[1][g][e] = bias1[g * NH + ecol + e];
        }

    unsigned* grel = sync;
    unsigned* gctr = sync + 16 + grp * 16;

    float c0[2] = {0.f, 0.f}, c1[2] = {0.f, 0.f};
    f32x4 acc[8][2];
    f32x4 Ast[3][4];
    f32x4 Bst[2][8];

    for (int p = 0; p <= NT; ++p) {
        const int pb_ = (p - 1) & 1;
        const int cb_ = p & 1;

        ZACC();
        if (Lg == 0) {
            if (p < NT) {
                const char* aH = hbB + (size_t)(0 + pb_) * HB2 + aoff;
                const char* aL = hbB + (size_t)(2 + pb_) * HB2 + aoff;
                // x prefix: cached loads + both x B-chunks, then fabric A(0),A(1)
                f32x4 xa0, xa1, xa2, xa3;
                f16x8 XAh[2], XAl[2];
                GLC(xa0, pxa0); GLC(xa1, pxa0 + 16);
                GLC(xa2, pxa1); GLC(xa3, pxa1 + 16);
                ISSB(0, xbh, xbl, GS0, CS0, 0, 0);
                ISSB(1, xbh, xbl, GS0, CS0, 1, 0);
                ISSA(0, 0);
                ISSA(1, 1024);
                VMW(16); // xa + XB0 done
                splitr(xa0, xa1, XAh[0], XAl[0]);
                splitr(xa2, xa3, XAh[1], XAl[1]);
                MFX(0, 0);
                VMW(8);  // XB1 done (A0,A1 in flight)
                MFX(1, 1);
                // h0-part: 4 k-steps
                ISSB(0, bh, bl, GS0, CS0, 0, 0);   ISSB(1, bh, bl, GS0, CS0, 1, 0);   ISSA(2, 2048);
                VMW(16); MFS(0, 0, 0); VMW(4); MFS(1, 0, 1);
                ISSB(0, bh, bl, GS0, CS0, 0, 64);  ISSB(1, bh, bl, GS0, CS0, 1, 64);  ISSA(0, 3072);
                VMW(12); MFS(0, 1, 0); VMW(4); MFS(1, 1, 1);
                ISSB(0, bh, bl, GS0, CS0, 0, 128); ISSB(1, bh, bl, GS0, CS0, 1, 128);
                VMW(8);  MFS(0, 2, 0); VMW(0); MFS(1, 2, 1);
                ISSB(0, bh, bl, GS0, CS0, 0, 192); ISSB(1, bh, bl, GS0, CS0, 1, 192);
                VMW(8);  MFS(0, 0, 0); VMW(0); MFS(1, 0, 1);
                DUMP();
            }
        } else {
            if (p >= 1) {
                // kq 0,1 read h0(p-1); kq 2,3 read h1(p-2)
                const char* aH = (kq < 2 ? hbB + (size_t)(0 + pb_) * HB2
                                         : hbB + (size_t)(4 + cb_) * HB2) + aoff;
                const char* aL = (kq < 2 ? hbB + (size_t)(2 + pb_) * HB2
                                         : hbB + (size_t)(6 + cb_) * HB2) + aoff;
                ISSA(0, 0);
                ISSA(1, 1024);
                ISSB(0, bh, bl, GS1, CS1, 0, 0);   ISSB(1, bh, bl, GS1, CS1, 1, 0);   ISSA(2, 2048);
                VMW(16); MFS(0, 0, 0); VMW(4); MFS(1, 0, 1);
                ISSB(0, bh, bl, GS1, CS1, 0, 64);  ISSB(1, bh, bl, GS1, CS1, 1, 64);  ISSA(0, 3072);
                VMW(12); MFS(0, 1, 0); VMW(4); MFS(1, 1, 1);
                ISSB(0, bh, bl, GS1, CS1, 0, 128); ISSB(1, bh, bl, GS1, CS1, 1, 128); ISSA(1, 4096);
                VMW(12); MFS(0, 2, 0); VMW(4); MFS(1, 2, 1);
                ISSB(0, bh, bl, GS1, CS1, 0, 192); ISSB(1, bh, bl, GS1, CS1, 1, 192); ISSA(2, 5120);
                VMW(12); MFS(0, 0, 0); VMW(4); MFS(1, 0, 1);
                ISSB(0, bh, bl, GS1, CS1, 0, 256); ISSB(1, bh, bl, GS1, CS1, 1, 256); ISSA(0, 6144);
                VMW(12); MFS(0, 1, 0); VMW(4); MFS(1, 1, 1);
                ISSB(0, bh, bl, GS1, CS1, 0, 320); ISSB(1, bh, bl, GS1, CS1, 1, 320); ISSA(1, 7168);
                VMW(12); MFS(0, 2, 0); VMW(4); MFS(1, 2, 1);
                ISSB(0, bh, bl, GS1, CS1, 0, 384); ISSB(1, bh, bl, GS1, CS1, 1, 384);
                VMW(8);  MFS(0, 0, 0); VMW(0); MFS(1, 0, 1);
                ISSB(0, bh, bl, GS1, CS1, 0, 448); ISSB(1, bh, bl, GS1, CS1, 1, 448);
                VMW(8);  MFS(0, 1, 0); VMW(0); MFS(1, 1, 1);
                DUMP();
            }
        }
        __syncthreads();

        // ---- cell L0: reduce ldsP[0..3], update c0, write h0(p) ----
        if (p < NT) {
            float gs[4][2];
#pragma unroll
            for (int g = 0; g < 4; ++g) { gs[g][0] = bE[0][g][0]; gs[g][1] = bE[0][g][1]; }
#pragma unroll
            for (int q = 0; q < 4; ++q)
#pragma unroll
                for (int g = 0; g < 4; ++g) {
                    float2 v = *(const float2*)&ldsP[q][er][g * 32 + ec2];
                    gs[g][0] += v.x; gs[g][1] += v.y;
                }
            f16 hh[2], hl[2];
#pragma unroll
            for (int e = 0; e < 2; ++e) {
                const float cn = sigf(gs[1][e]) * c0[e] + sigf(gs[0][e]) * tanhf(gs[2][e]);
                c0[e] = cn;
                const float h = sigf(gs[3][e]) * tanhf(cn);
                hh[e] = (f16)h;
                hl[e] = (f16)(h - (float)hh[e]);
            }
            cstore2(hb + (size_t)(0 + cb_) * HBUF + eoff, hh[0], hh[1]);
            cstore2(hb + (size_t)(2 + cb_) * HBUF + eoff, hl[0], hl[1]);
        }
        // ---- cell L1: reduce ldsP[4..7], update c1, write h1(p-1) ----
        if (p >= 1) {
            float gs[4][2];
#pragma unroll
            for (int g = 0; g < 4; ++g) { gs[g][0] = bE[1][g][0]; gs[g][1] = bE[1][g][1]; }
#pragma unroll
            for (int q = 4; q < 8; ++q)
#pragma unroll
                for (int g = 0; g < 4; ++g) {
                    float2 v = *(const float2*)&ldsP[q][er][g * 32 + ec2];
                    gs[g][0] += v.x; gs[g][1] += v.y;
                }
            f16 hh[2], hl[2];
            float hv[2];
#pragma unroll
            for (int e = 0; e < 2; ++e) {
                const float cn = sigf(gs[1][e]) * c1[e] + sigf(gs[0][e]) * tanhf(gs[2][e]);
                c1[e] = cn;
                const float h = sigf(gs[3][e]) * tanhf(cn);
                hv[e] = h;
                hh[e] = (f16)h;
                hl[e] = (f16)(h - (float)hh[e]);
            }
            cstore2(hb + (size_t)(4 + pb_) * HBUF + eoff, hh[0], hh[1]);
            cstore2(hb + (size_t)(6 + pb_) * HBUF + eoff, hl[0], hl[1]);
            if (p == NT) {
                const size_t off = (size_t)(row0 + er) * NH + ecol;
                h1f[off] = hv[0];
                h1f[off + 1] = hv[1];
            }
        }

        // ---- two-level grid barrier (32-way group fan-in, 8 leaders) ----
        if (p < NT) {
            __syncthreads(); // drains each thread's vmcnt: h stores visible at MALL
            if (tid == 0) {
                unsigned v = __hip_atomic_fetch_add(gctr, 1u, __ATOMIC_RELAXED, __HIP_MEMORY_SCOPE_AGENT);
                if (v == 32u * (unsigned)(p + 1) - 1u) {
                    __hip_atomic_fetch_add(grel, 1u, __ATOMIC_RELAXED, __HIP_MEMORY_SCOPE_AGENT);
                }
                const unsigned tgt = 8u * (unsigned)(p + 1);
                while (__hip_atomic_load(grel, __ATOMIC_RELAXED, __HIP_MEMORY_SCOPE_AGENT) < tgt) {
                    __builtin_amdgcn_s_sleep(1);
                }
            }
            __syncthreads();
            asm volatile("" ::: "memory");
        }
        pxa0 += 512; // advance x to next timestep
        pxa1 += 512;
    }
}

// ---------------- binarize + FC ----------------
__global__ __launch_bounds__(256) void fc_kernel(
    const float* __restrict__ h1f, const float* __restrict__ Wfc,
    const float* __restrict__ bfc, float* __restrict__ out)
{
    const int t = blockIdx.x * blockDim.x + threadIdx.x; // 0..16383
    const int b = t >> 5;
    const int o = t & 31;
    const float4* hr = (const float4*)(h1f + (size_t)b * NH);
    const float4* wr = (const float4*)(Wfc + (size_t)o * NH);
    float s = 0.f;
#pragma unroll 4
    for (int j = 0; j < NH / 4; ++j) {
        float4 h4 = hr[j];
        float4 w4 = wr[j];
        s += (h4.x > 0.f ? w4.x : 0.f) + (h4.y > 0.f ? w4.y : 0.f)
           + (h4.z > 0.f ? w4.z : 0.f) + (h4.w > 0.f ? w4.w : 0.f);
    }
    out[t] = s + bfc[o];
}

extern "C" void kernel_launch(void* const* d_in, const int* in_sizes, int n_in,
                              void* d_out, int out_size, void* d_ws, size_t ws_size,
                              hipStream_t stream) {
    const float* x    = (const float*)d_in[0];
    const float* Wih0 = (const float*)d_in[1];
    const float* Whh0 = (const float*)d_in[2];
    const float* bih0 = (const float*)d_in[3];
    const float* bhh0 = (const float*)d_in[4];
    const float* Wih1 = (const float*)d_in[5];
    const float* Whh1 = (const float*)d_in[6];
    const float* bih1 = (const float*)d_in[7];
    const float* bhh1 = (const float*)d_in[8];
    const float* Wfc  = (const float*)d_in[9];
    const float* bfc  = (const float*)d_in[10];
    float* out = (float*)d_out;
    (void)in_sizes; (void)n_in; (void)out_size; (void)ws_size;

    // workspace layout (~19 MB)
    char* w = (char*)d_ws;
    unsigned* sync = (unsigned*)w;                               // 8 KB sync region
    f16* hb = (f16*)(w + 8192);                                  // 4 MB h ping-pong (hi/lo)
    char* after_hb = w + 8192 + (size_t)8 * HBUF * sizeof(f16);
    float* h1f = (float*)after_hb;                               // 1 MB
    float* bias0 = (float*)(after_hb + (size_t)NB * NH * 4);
    float* bias1 = bias0 + NGC;
    f16* W0h = (f16*)(bias1 + NGC);
    f16* W0l = W0h + (size_t)NGC * K0;
    f16* W1h = W0l + (size_t)NGC * K0;
    f16* W1l = W1h + (size_t)NGC * K1;

    // zero: sync counters + h state (h(-1)=0); replayed each graph launch
    hipMemsetAsync(d_ws, 0, 8192 + (size_t)8 * HBUF * sizeof(f16), stream);

    prep_kernel<<<2048, 256, 0, stream>>>(Wih0, Whh0, bih0, bhh0, Wih1, Whh1, bih1, bhh1,
                                          W0h, W0l, W1h, W1l, bias0, bias1);

    lstm_kernel<<<NBLK, NTHR, 0, stream>>>(x, W0h, W0l, W1h, W1l, bias0, bias1,
                                           hb, sync, h1f);

    fc_kernel<<<64, 256, 0, stream>>>(h1f, Wfc, bfc, out);
}

// Round 6
// 47962.402 us; speedup vs baseline: 1.7033x; 1.1064x over previous
//
#include <hip/hip_runtime.h>
#include <hip/hip_bf16.h>

// LSTM (2-layer, T=1024) + STE binarize + FC, MI355X.
// Round 6: R3's proven streaming k-step pipeline (12 loads -> vmcnt(12) ->
// 24 MFMAs, lookahead-1), tile 32 rows x 32 h-cols (fabric A-traffic halved
// vs R3), REAL-XCD placement via s_getreg(XCC_ID)+slot claim so weight
// slices (1.7 MB/XCD) are guaranteed L2-resident, packed hi|lo h cells
// (32 B/lane) for full-line fabric streams.

typedef _Float16 f16;
typedef __attribute__((ext_vector_type(8))) _Float16 f16x8;
typedef __attribute__((ext_vector_type(4))) float f32x4;

#define MFMA(a, b, c) __builtin_amdgcn_mfma_f32_16x16x32_f16((a), (b), (c), 0, 0, 0)
#define H8(v) __builtin_bit_cast(f16x8, v)

// MALL-coherent bypass load (h state)
#define GLB(dst, ptr) asm volatile("global_load_dwordx4 %0, %1, off sc0 sc1" : "=v"(dst) : "v"(ptr) : "memory")
// cached load (weights / x)
#define GLC(dst, ptr) asm volatile("global_load_dwordx4 %0, %1, off" : "=v"(dst) : "v"(ptr) : "memory")
#define VMW(n) do { asm volatile("s_waitcnt vmcnt(" #n ")" ::: "memory"); __builtin_amdgcn_sched_barrier(0); } while (0)

#define NB 512
#define NT 1024
#define NF 128
#define NH 512
#define NGC 2048
#define K0 640       // NH + NF
#define K1 1024      // 2*NH
#define NBLK 256
#define NTHR 512
#define MB 1048576   // bytes per packed h buffer (512*512*4B)
// packed h cell layout: [rowblk(32)][kblk(16)][lane(64)][hi 16B | lo 16B]
#define RBS 32768    // rowblk stride bytes (16 kblk * 2048)
#define KBS 2048     // kblk stride bytes (64 lanes * 32)
// weight byte strides
#define GS0 655360   // gate stride W0 (NH*K0*2)
#define CS0 20480    // 16-col stride W0
#define GS1 1048576  // gate stride W1 (NH*K1*2)
#define CS1 32768    // 16-col stride W1
#define XR  8388608  // x row-block stride (16*NT*NF*4)
#define GETREG_XCC 63508  // hwreg(HW_REG_XCC_ID=20,0,32)

__device__ __forceinline__ float sigf(float v) { return 1.0f / (1.0f + expf(-v)); }

// coherent 4B (f16x2) write-through store
__device__ __forceinline__ void cstore2(void* p, f16 a, f16 b) {
    union { f16 h[2]; unsigned u; } x;
    x.h[0] = a; x.h[1] = b;
    __hip_atomic_store((unsigned*)p, x.u, __ATOMIC_RELAXED, __HIP_MEMORY_SCOPE_AGENT);
}

__device__ __forceinline__ void splitr(f32x4 u0, f32x4 u1, f16x8& hi, f16x8& lo) {
#pragma unroll
    for (int e = 0; e < 4; ++e) {
        float v = u0[e];
        f16 h = (f16)v;
        hi[e] = h;
        lo[e] = (f16)(v - (float)h);
    }
#pragma unroll
    for (int e = 0; e < 4; ++e) {
        float v = u1[e];
        f16 h = (f16)v;
        hi[4 + e] = h;
        lo[4 + e] = (f16)(v - (float)h);
    }
}

// ---------------- prep: split weights into packed hi/lo f16, sum biases ----------------
__global__ __launch_bounds__(256) void prep_kernel(
    const float* __restrict__ Wih0, const float* __restrict__ Whh0,
    const float* __restrict__ bih0, const float* __restrict__ bhh0,
    const float* __restrict__ Wih1, const float* __restrict__ Whh1,
    const float* __restrict__ bih1, const float* __restrict__ bhh1,
    f16* __restrict__ W0h, f16* __restrict__ W0l,
    f16* __restrict__ W1h, f16* __restrict__ W1l,
    float* __restrict__ bias0, float* __restrict__ bias1)
{
    const int stride = gridDim.x * blockDim.x;
    const int idx = blockIdx.x * blockDim.x + threadIdx.x;
    const int total0 = NGC * K0;
    for (int i = idx; i < total0; i += stride) {
        int gc = i / K0, k = i - gc * K0;
        float w = (k < NH) ? Whh0[gc * NH + k] : Wih0[gc * NF + (k - NH)];
        f16 h = (f16)w;
        W0h[i] = h;
        W0l[i] = (f16)(w - (float)h);
    }
    const int total1 = NGC * K1;
    for (int i = idx; i < total1; i += stride) {
        int gc = i / K1, k = i - gc * K1;
        float w = (k < NH) ? Wih1[gc * NH + k] : Whh1[gc * NH + (k - NH)];
        f16 h = (f16)w;
        W1h[i] = h;
        W1l[i] = (f16)(w - (float)h);
    }
    for (int i = idx; i < NGC; i += stride) {
        bias0[i] = bih0[i] + bhh0[i];
        bias1[i] = bih1[i] + bhh1[i];
    }
}

struct Stg { f32x4 A[4]; f32x4 B[8]; };

// A k-step: 2 rowblocks x (hi,lo) = 4 bypass loads (packed 32B cells)
#define ISSA(S, aB, ko) do { \
    GLB(S.A[0], (aB) + (ko));       GLB(S.A[1], (aB) + (ko) + 16); \
    GLB(S.A[2], (aB) + (ko) + RBS); GLB(S.A[3], (aB) + (ko) + RBS + 16); \
} while (0)

// B k-step: 2 gates x 2 col-halves x (hi,lo) = 8 cached loads
#define ISSB(S, bh_, bl_, GS, CS, ko) do { \
    GLC(S.B[0], (bh_) + (ko));               GLC(S.B[1], (bl_) + (ko)); \
    GLC(S.B[2], (bh_) + (CS) + (ko));        GLC(S.B[3], (bl_) + (CS) + (ko)); \
    GLC(S.B[4], (bh_) + (GS) + (ko));        GLC(S.B[5], (bl_) + (GS) + (ko)); \
    GLC(S.B[6], (bh_) + (GS) + (CS) + (ko)); GLC(S.B[7], (bl_) + (GS) + (CS) + (ko)); \
} while (0)

// 24 MFMAs: 4 col-frags (2 gates x 2 halves) x 2 row-frags x 3 split-products
#define STEPK(S) do { \
    _Pragma("unroll") for (int cf = 0; cf < 4; ++cf) \
    _Pragma("unroll") for (int rf = 0; rf < 2; ++rf) { \
        acc[cf][rf] = MFMA(H8(S.A[rf * 2]),     H8(S.B[cf * 2]),     acc[cf][rf]); \
        acc[cf][rf] = MFMA(H8(S.A[rf * 2]),     H8(S.B[cf * 2 + 1]), acc[cf][rf]); \
        acc[cf][rf] = MFMA(H8(S.A[rf * 2 + 1]), H8(S.B[cf * 2]),     acc[cf][rf]); \
    } } while (0)

// x variant: A from split registers
#define STEPX(S) do { \
    _Pragma("unroll") for (int cf = 0; cf < 4; ++cf) \
    _Pragma("unroll") for (int rf = 0; rf < 2; ++rf) { \
        acc[cf][rf] = MFMA(XAh[rf], H8(S.B[cf * 2]),     acc[cf][rf]); \
        acc[cf][rf] = MFMA(XAh[rf], H8(S.B[cf * 2 + 1]), acc[cf][rf]); \
        acc[cf][rf] = MFMA(XAl[rf], H8(S.B[cf * 2]),     acc[cf][rf]); \
    } } while (0)

#define ZACC() do { f32x4 _z = {0.f, 0.f, 0.f, 0.f}; \
    _Pragma("unroll") for (int cf = 0; cf < 4; ++cf) { acc[cf][0] = _z; acc[cf][1] = _z; } } while (0)

#define DUMP() do { \
    _Pragma("unroll") for (int cf = 0; cf < 4; ++cf) \
    _Pragma("unroll") for (int rf = 0; rf < 2; ++rf) \
    _Pragma("unroll") for (int rg = 0; rg < 4; ++rg) \
        ldsG[kq][g0 + (cf >> 1)][rf * 16 + kg * 4 + rg][(cf & 1) * 16 + lm] = acc[cf][rf][rg]; \
} while (0)

// ---------------- main persistent LSTM kernel ----------------
__global__ __launch_bounds__(NTHR, 2) void lstm_kernel(
    const float* __restrict__ x,
    const f16* __restrict__ W0h, const f16* __restrict__ W0l,
    const f16* __restrict__ W1h, const f16* __restrict__ W1l,
    const float* __restrict__ bias0, const float* __restrict__ bias1,
    char* hbB, unsigned* sync,
    float* __restrict__ h1f)
{
    const int tid = threadIdx.x;
    const int lane = tid & 63;
    const int wv = tid >> 6;     // 0..7
    const int gp = wv & 1;       // gate pair: 0={i,f} 1={g,o}
    const int kq = wv >> 1;      // K-quarter 0..3
    const int kg = lane >> 4;
    const int lm = lane & 15;

    __shared__ float ldsG[4][4][32][36]; // [kq][gate][row][col32+pad] partials (73728 B)
    __shared__ char ldsPad[12288];       // force 1 block/CU (total 86016 > 81920)
    __shared__ int sSlot;

    // ---- real-XCD placement: getreg + slot claim (<=32 blocks/XCD by 1/CU) ----
    const unsigned xcd = (unsigned)__builtin_amdgcn_s_getreg(GETREG_XCC) & 7u;
    unsigned* gbar    = sync;
    unsigned* slotCtr = sync + 128 + xcd * 64;
    if (tid == 0) sSlot = (int)__hip_atomic_fetch_add(slotCtr, 1u, __ATOMIC_RELAXED, __HIP_MEMORY_SCOPE_AGENT);
    __syncthreads();
    const int slot = sSlot & 31;
    if (slot < 0) ldsPad[0] = (char)tid; // keep pad alive (never true)
    const int rowTile = slot >> 1;                // 0..15 (32 rows)
    const int colTile = (int)xcd * 2 + (slot & 1); // 0..15 (32 h-cols)
    const int row0 = rowTile * 32;
    const int rb0 = rowTile * 2; // rowblock index

    const int g0 = gp * 2;
    const int gcb = g0 * NH + colTile * 32 + lm; // gate-col base (ch=0)

    // B base pointers (bytes)
    const char* b0h = (const char*)W0h + ((size_t)gcb * K0 + kq * 128 + kg * 8) * 2;
    const char* b0l = (const char*)W0l + ((size_t)gcb * K0 + kq * 128 + kg * 8) * 2;
    const char* b1h = (const char*)W1h + ((size_t)gcb * K1 + kq * 256 + kg * 8) * 2;
    const char* b1l = (const char*)W1l + ((size_t)gcb * K1 + kq * 256 + kg * 8) * 2;
    const char* xbh = (const char*)W0h + ((size_t)gcb * K0 + NH + kq * 32 + kg * 8) * 2;
    const char* xbl = (const char*)W0l + ((size_t)gcb * K0 + NH + kq * 32 + kg * 8) * 2;

    // x A pointer (row0+lm), advances 512 B per phase
    const char* pxa = (const char*)x + ((size_t)(row0 + lm) * NT * NF + kq * 32 + kg * 8) * 4;

    // A byte offsets within packed h buffers
    const size_t aoff0 = (size_t)rb0 * RBS + (size_t)kq * 4 * KBS + (size_t)lane * 32;        // L0: kblk kq*4..+3
    const size_t aoff1 = (size_t)rb0 * RBS + (size_t)(kq & 1) * 8 * KBS + (size_t)lane * 32;  // L1: kblk (kq&1)*8..+7

    // epilogue mapping: 32 rows x 32 cols, thread -> (er, 2 cols)
    const int er = tid >> 4;          // 0..31
    const int ec = (tid & 15) * 2;    // 0..30
    const int r = row0 + er;
    const size_t sbyte = (size_t)(r >> 4) * RBS + (size_t)colTile * KBS
                       + (size_t)(((ec >> 3) & 3) * 16 + (r & 15)) * 32 + (ec & 7) * 2;
    const int ecol = colTile * 32 + ec;
    float bE[2][4][2];
#pragma unroll
    for (int g = 0; g < 4; ++g)
#pragma unroll
        for (int e = 0; e < 2; ++e) {
            bE[0][g][e] = bias0[g * NH + ecol + e];
            bE[1][g][e] = bias1[g * NH + ecol + e];
        }

    float c0[2] = {0.f, 0.f}, c1[2] = {0.f, 0.f};
    f32x4 acc[4][2];
    Stg sA, sB;
    f16x8 XAh[2], XAl[2];

    for (int p = 0; p <= NT; ++p) {
        const int pb_ = (p - 1) & 1;
        const int cb_ = p & 1;
        const size_t xoff = (size_t)p * 512;

        // ================= L0 GEMM: x (1 step) + h0(p-1) (4 steps) =================
        if (p < NT) {
            ZACC();
            const char* a0B = hbB + (size_t)pb_ * MB + aoff0;
            f32x4 xa0, xa1, xa2, xa3;
            GLC(xa0, pxa + xoff); GLC(xa1, pxa + xoff + 16);
            GLC(xa2, pxa + xoff + XR); GLC(xa3, pxa + xoff + XR + 16);
            ISSB(sA, xbh, xbl, GS0, CS0, 0);
            ISSA(sB, a0B, 0); ISSB(sB, b0h, b0l, GS0, CS0, 0);
            VMW(12);
            splitr(xa0, xa1, XAh[0], XAl[0]);
            splitr(xa2, xa3, XAh[1], XAl[1]);
            STEPX(sA);
            ISSA(sA, a0B, 2048); ISSB(sA, b0h, b0l, GS0, CS0, 64);
            VMW(12); STEPK(sB);
            ISSA(sB, a0B, 4096); ISSB(sB, b0h, b0l, GS0, CS0, 128);
            VMW(12); STEPK(sA);
            ISSA(sA, a0B, 6144); ISSB(sA, b0h, b0l, GS0, CS0, 192);
            VMW(12); STEPK(sB);
            VMW(0);  STEPK(sA);
            DUMP();
        }
        __syncthreads();
        // ---- cell L0 ----
        if (p < NT) {
            float gs[4][2];
#pragma unroll
            for (int g = 0; g < 4; ++g) { gs[g][0] = bE[0][g][0]; gs[g][1] = bE[0][g][1]; }
#pragma unroll
            for (int q = 0; q < 4; ++q)
#pragma unroll
                for (int g = 0; g < 4; ++g) {
                    float2 v = *(const float2*)&ldsG[q][g][er][ec];
                    gs[g][0] += v.x; gs[g][1] += v.y;
                }
            f16 hh[2], hl[2];
#pragma unroll
            for (int e = 0; e < 2; ++e) {
                const float cn = sigf(gs[1][e]) * c0[e] + sigf(gs[0][e]) * tanhf(gs[2][e]);
                c0[e] = cn;
                const float h = sigf(gs[3][e]) * tanhf(cn);
                hh[e] = (f16)h;
                hl[e] = (f16)(h - (float)hh[e]);
            }
            char* d = hbB + (size_t)cb_ * MB + sbyte;
            cstore2(d, hh[0], hh[1]);
            cstore2(d + 16, hl[0], hl[1]);
        }
        __syncthreads();
        // ================= L1 GEMM: 8 steps (kq<2: h0(p-1); kq>=2: h1(p-2)) =================
        if (p >= 1) {
            ZACC();
            const char* a1B = hbB + (size_t)(kq < 2 ? pb_ : 2 + cb_) * MB + aoff1;
            ISSA(sA, a1B, 0);     ISSB(sA, b1h, b1l, GS1, CS1, 0);
            ISSA(sB, a1B, 2048);  ISSB(sB, b1h, b1l, GS1, CS1, 64);
            VMW(12); STEPK(sA);
            ISSA(sA, a1B, 4096);  ISSB(sA, b1h, b1l, GS1, CS1, 128);
            VMW(12); STEPK(sB);
            ISSA(sB, a1B, 6144);  ISSB(sB, b1h, b1l, GS1, CS1, 192);
            VMW(12); STEPK(sA);
            ISSA(sA, a1B, 8192);  ISSB(sA, b1h, b1l, GS1, CS1, 256);
            VMW(12); STEPK(sB);
            ISSA(sB, a1B, 10240); ISSB(sB, b1h, b1l, GS1, CS1, 320);
            VMW(12); STEPK(sA);
            ISSA(sA, a1B, 12288); ISSB(sA, b1h, b1l, GS1, CS1, 384);
            VMW(12); STEPK(sB);
            ISSA(sB, a1B, 14336); ISSB(sB, b1h, b1l, GS1, CS1, 448);
            VMW(12); STEPK(sA);
            VMW(0);  STEPK(sB);
            DUMP();
        }
        __syncthreads();
        // ---- cell L1 ----
        if (p >= 1) {
            float gs[4][2];
#pragma unroll
            for (int g = 0; g < 4; ++g) { gs[g][0] = bE[1][g][0]; gs[g][1] = bE[1][g][1]; }
#pragma unroll
            for (int q = 0; q < 4; ++q)
#pragma unroll
                for (int g = 0; g < 4; ++g) {
                    float2 v = *(const float2*)&ldsG[q][g][er][ec];
                    gs[g][0] += v.x; gs[g][1] += v.y;
                }
            f16 hh[2], hl[2];
            float hv[2];
#pragma unroll
            for (int e = 0; e < 2; ++e) {
                const float cn = sigf(gs[1][e]) * c1[e] + sigf(gs[0][e]) * tanhf(gs[2][e]);
                c1[e] = cn;
                const float h = sigf(gs[3][e]) * tanhf(cn);
                hv[e] = h;
                hh[e] = (f16)h;
                hl[e] = (f16)(h - (float)hh[e]);
            }
            char* d = hbB + (size_t)(2 + pb_) * MB + sbyte;
            cstore2(d, hh[0], hh[1]);
            cstore2(d + 16, hl[0], hl[1]);
            if (p == NT) {
                const size_t off = (size_t)r * NH + ecol;
                h1f[off] = hv[0];
                h1f[off + 1] = hv[1];
            }
        }
        // ================= grid barrier =================
        if (p < NT) {
            __syncthreads(); // per-thread vmcnt drained; write-through stores visible
            if (tid == 0) {
                __hip_atomic_fetch_add(gbar, 1u, __ATOMIC_RELAXED, __HIP_MEMORY_SCOPE_AGENT);
                const unsigned tgt = (unsigned)(p + 1) * NBLK;
                while (__hip_atomic_load(gbar, __ATOMIC_RELAXED, __HIP_MEMORY_SCOPE_AGENT) < tgt) {
                    __builtin_amdgcn_s_sleep(1);
                }
            }
            __syncthreads();
            asm volatile("" ::: "memory");
        }
    }
}

// ---------------- binarize + FC ----------------
__global__ __launch_bounds__(256) void fc_kernel(
    const float* __restrict__ h1f, const float* __restrict__ Wfc,
    const float* __restrict__ bfc, float* __restrict__ out)
{
    const int t = blockIdx.x * blockDim.x + threadIdx.x;
    const int b = t >> 5;
    const int o = t & 31;
    const float4* hr = (const float4*)(h1f + (size_t)b * NH);
    const float4* wr = (const float4*)(Wfc + (size_t)o * NH);
    float s = 0.f;
#pragma unroll 4
    for (int j = 0; j < NH / 4; ++j) {
        float4 h4 = hr[j];
        float4 w4 = wr[j];
        s += (h4.x > 0.f ? w4.x : 0.f) + (h4.y > 0.f ? w4.y : 0.f)
           + (h4.z > 0.f ? w4.z : 0.f) + (h4.w > 0.f ? w4.w : 0.f);
    }
    out[t] = s + bfc[o];
}

extern "C" void kernel_launch(void* const* d_in, const int* in_sizes, int n_in,
                              void* d_out, int out_size, void* d_ws, size_t ws_size,
                              hipStream_t stream) {
    const float* x    = (const float*)d_in[0];
    const float* Wih0 = (const float*)d_in[1];
    const float* Whh0 = (const float*)d_in[2];
    const float* bih0 = (const float*)d_in[3];
    const float* bhh0 = (const float*)d_in[4];
    const float* Wih1 = (const float*)d_in[5];
    const float* Whh1 = (const float*)d_in[6];
    const float* bih1 = (const float*)d_in[7];
    const float* bhh1 = (const float*)d_in[8];
    const float* Wfc  = (const float*)d_in[9];
    const float* bfc  = (const float*)d_in[10];
    float* out = (float*)d_out;
    (void)in_sizes; (void)n_in; (void)out_size; (void)ws_size;

    // workspace layout (~19 MB)
    char* w = (char*)d_ws;
    unsigned* sync = (unsigned*)w;                 // 8 KB sync region
    char* hb = w + 8192;                           // 4 x 1 MB packed h buffers (h0 pp, h1 pp)
    char* after_hb = hb + (size_t)4 * MB;
    float* h1f = (float*)after_hb;                 // 1 MB
    float* bias0 = (float*)(after_hb + (size_t)NB * NH * 4);
    float* bias1 = bias0 + NGC;
    f16* W0h = (f16*)(bias1 + NGC);
    f16* W0l = W0h + (size_t)NGC * K0;
    f16* W1h = W0l + (size_t)NGC * K0;
    f16* W1l = W1h + (size_t)NGC * K1;

    // zero sync counters + h buffers (h(-1)=0); replayed each graph launch
    hipMemsetAsync(d_ws, 0, 8192 + (size_t)4 * MB, stream);

    prep_kernel<<<2048, 256, 0, stream>>>(Wih0, Whh0, bih0, bhh0, Wih1, Whh1, bih1, bhh1,
                                          W0h, W0l, W1h, W1l, bias0, bias1);

    lstm_kernel<<<NBLK, NTHR, 0, stream>>>(x, W0h, W0l, W1h, W1l, bias0, bias1,
                                           hb, sync, h1f);

    fc_kernel<<<64, 256, 0, stream>>>(h1f, Wfc, bfc, out);
}